// Round 10
// baseline (63.509 us; speedup 1.0000x reference)
//
#include <hip/hip_runtime.h>

#define H_STEPS 200
#define DT 0.01f
#define K_SPRING 100.0f
#define NQ (H_STEPS / 4)   // 50 float4 per row

typedef float vf4 __attribute__((ext_vector_type(4)));   // builtin-compatible

__device__ __forceinline__ void step(float u, float& x1, float& v1,
                                     float& x2, float& v2) {
    float pen     = x1 + 1.0f - x2;
    float contact = fmaxf(pen, 0.0f);
    float Fc      = -K_SPRING * contact;
    float F1      = u + Fc - v1;      // C = 1
    float F2      = -Fc - v2;
    v1 += F1 * DT;
    v2 += F2 * DT;
    x1 += v1 * DT;
    x2 += v2 * DT;
}

// R3 structure (best measured base: array prefetch, compiler-scheduled depth)
// + NON-TEMPORAL loads: 512 concurrent row-streams/CU thrash the 32KB L1's
// allocation path (~448KB hot lines vs 32KB). nt bypasses L1 allocation for
// this read-once stream; same-line requests MSHR-coalesce while in flight.
// vf4 = clang ext_vector_type (HIP float4 is a struct the builtin rejects).
__global__ __launch_bounds__(256, 2)   // 2 waves/EU -> 256-VGPR budget
void pushing_env_kernel(const float* __restrict__ u_seq,
                        const float* __restrict__ x1_0,
                        const float* __restrict__ v1_0,
                        const float* __restrict__ x2_0,
                        const float* __restrict__ v2_0,
                        const float* __restrict__ goal,
                        float* __restrict__ out, int B) {
    int b = blockIdx.x * blockDim.x + threadIdx.x;

    float x1 = __builtin_nontemporal_load(&x1_0[b]);
    float v1 = __builtin_nontemporal_load(&v1_0[b]);
    float x2 = __builtin_nontemporal_load(&x2_0[b]);
    float v2 = __builtin_nontemporal_load(&v2_0[b]);
    const float g = goal[0];

    const vf4* u = reinterpret_cast<const vf4*>(u_seq + (size_t)b * H_STEPS);

    vf4 r[NQ];
    #pragma unroll
    for (int q = 0; q < NQ; ++q)
        r[q] = __builtin_nontemporal_load(&u[q]);   // all 50 issued up front

    #pragma unroll
    for (int q = 0; q < NQ; ++q) {
        step(r[q].x, x1, v1, x2, v2);
        step(r[q].y, x1, v1, x2, v2);
        step(r[q].z, x1, v1, x2, v2);
        step(r[q].w, x1, v1, x2, v2);
    }

    float d = x2 - g;
    out[b]         = d * d;   // loss
    out[B + b]     = x1;
    out[2 * B + b] = x2;
}

extern "C" void kernel_launch(void* const* d_in, const int* in_sizes, int n_in,
                              void* d_out, int out_size, void* d_ws, size_t ws_size,
                              hipStream_t stream) {
    const float* u_seq = (const float*)d_in[0];
    const float* x1_0  = (const float*)d_in[1];
    const float* v1_0  = (const float*)d_in[2];
    const float* x2_0  = (const float*)d_in[3];
    const float* v2_0  = (const float*)d_in[4];
    const float* goal  = (const float*)d_in[5];
    float* out = (float*)d_out;

    const int B = in_sizes[1];  // 131072
    const int block = 256;
    const int grid = B / block; // 512 blocks
    pushing_env_kernel<<<grid, block, 0, stream>>>(u_seq, x1_0, v1_0, x2_0,
                                                   v2_0, goal, out, B);
}

// Round 11
// 24.658 us; speedup vs baseline: 2.5756x; 2.5756x over previous
//
#include <hip/hip_runtime.h>

#define H_STEPS 200
#define DT 0.01f
#define K_SPRING 100.0f

__device__ __forceinline__ void step(float u, float& x1, float& v1,
                                     float& x2, float& v2) {
    float pen     = x1 + 1.0f - x2;
    float contact = fmaxf(pen, 0.0f);
    float Fc      = -K_SPRING * contact;
    float F1      = u + Fc - v1;      // C = 1
    float F2      = -Fc - v2;
    v1 += F1 * DT;
    v2 += F2 * DT;
    x1 += v1 * DT;
    x2 += v2 * DT;
}

// 1-wave blocks, 5-slot LDS ring of global_load_lds chunks.
// Chunk = 16 steps x 64 rows = 4KB = 4 width-16 DMA instrs (16 rows x 64B
// contiguous each; every 128B line requested exactly once -> no L1 reuse
// needed, unlike the divergent pattern where 8 waves x 64 hot lines thrash
// the 256-line L1 and re-pull ~8x through L2 = the ~24us plateau).
// Ring: consume chunk c while c+1..c+4 in flight; hand-counted vmcnt; no
// __syncthreads, no drains. 20KB LDS -> 8 blocks/CU x 256 CU = 2048 blocks
// = exactly one residency, no tail.
__global__ __launch_bounds__(64)
void pushing_env_kernel(const float* __restrict__ u_seq,
                        const float* __restrict__ x1_0,
                        const float* __restrict__ v1_0,
                        const float* __restrict__ x2_0,
                        const float* __restrict__ v2_0,
                        const float* __restrict__ goal,
                        float* __restrict__ out, int B) {
    __shared__ float4 lds4[5 * 256];   // 5 slots x 4KB
    const int lane = threadIdx.x;      // 0..63, one wave
    const int b0   = blockIdx.x * 64;
    const int b    = b0 + lane;

    // States issue first: oldest in vmcnt order, retired by the first
    // counted wait. goal is a scalar s_load (lgkmcnt, not vmcnt).
    float x1 = x1_0[b];
    float v1 = v1_0[b];
    float x2 = x2_0[b];
    float v2 = v2_0[b];
    const float g = goal[0];

    const int rsel = lane & 15;   // row within 16-row group
    const int qsel = lane >> 4;   // qword slot 0..3

    // DMA chunk c into ring slot s: instr j covers rows j*16..j*16+15,
    // qwords c*4..c*4+3 (64B contiguous per row). LDS dest is linear
    // (wave-uniform base + lane*16); mapping lands row l, qword q at
    // float4 index (l>>4)*64 + q*16 + (l&15).
#define ISSUE(c, s) { \
    _Pragma("unroll") \
    for (int j = 0; j < 4; ++j) { \
        const float* gp = u_seq + \
            (size_t)(b0 + j * 16 + rsel) * H_STEPS + ((c) * 4 + qsel) * 4; \
        float4* lp = &lds4[(s) * 256 + j * 64]; \
        __builtin_amdgcn_global_load_lds( \
            (const __attribute__((address_space(1))) void*)gp, \
            (__attribute__((address_space(3))) void*)lp, 16, 0, 0); \
    } }

    // Consume chunk c from slot s after waiting to at most N outstanding.
    // Reads are structurally conflict-free (8 lanes per 4-bank set = b128
    // minimum). sched_barrier pins read/DMA order for slot reuse.
#define CONSUME(c, s, N) { \
    asm volatile("s_waitcnt vmcnt(" #N ")" ::: "memory"); \
    _Pragma("unroll") \
    for (int q = 0; q < 4; ++q) { \
        float4 u4 = lds4[(s) * 256 + (lane >> 4) * 64 + q * 16 + (lane & 15)]; \
        step(u4.x, x1, v1, x2, v2); \
        step(u4.y, x1, v1, x2, v2); \
        step(u4.z, x1, v1, x2, v2); \
        step(u4.w, x1, v1, x2, v2); \
    } \
    __builtin_amdgcn_sched_barrier(0); }

    ISSUE(0, 0) ISSUE(1, 1) ISSUE(2, 2) ISSUE(3, 3)   // 16 loads in flight

    CONSUME(0, 0, 12) ISSUE(4, 4)
    CONSUME(1, 1, 12) ISSUE(5, 0)
    CONSUME(2, 2, 12) ISSUE(6, 1)
    CONSUME(3, 3, 12) ISSUE(7, 2)
    CONSUME(4, 4, 12) ISSUE(8, 3)
    CONSUME(5, 0, 12) ISSUE(9, 4)
    CONSUME(6, 1, 12) ISSUE(10, 0)
    CONSUME(7, 2, 12) ISSUE(11, 1)

    // Tail (steps 192..199): own row, 2 direct loads, issued last.
    const float4* urow = reinterpret_cast<const float4*>(
        u_seq + (size_t)b * H_STEPS);
    float4 t0 = urow[48];
    float4 t1 = urow[49];

    CONSUME(8, 3, 14)
    CONSUME(9, 4, 10)
    CONSUME(10, 0, 6)
    CONSUME(11, 1, 2)

    asm volatile("s_waitcnt vmcnt(0)" ::: "memory");
    step(t0.x, x1, v1, x2, v2);
    step(t0.y, x1, v1, x2, v2);
    step(t0.z, x1, v1, x2, v2);
    step(t0.w, x1, v1, x2, v2);
    step(t1.x, x1, v1, x2, v2);
    step(t1.y, x1, v1, x2, v2);
    step(t1.z, x1, v1, x2, v2);
    step(t1.w, x1, v1, x2, v2);

    float d = x2 - g;
    out[b]         = d * d;   // loss
    out[B + b]     = x1;
    out[2 * B + b] = x2;
}

extern "C" void kernel_launch(void* const* d_in, const int* in_sizes, int n_in,
                              void* d_out, int out_size, void* d_ws, size_t ws_size,
                              hipStream_t stream) {
    const float* u_seq = (const float*)d_in[0];
    const float* x1_0  = (const float*)d_in[1];
    const float* v1_0  = (const float*)d_in[2];
    const float* x2_0  = (const float*)d_in[3];
    const float* v2_0  = (const float*)d_in[4];
    const float* goal  = (const float*)d_in[5];
    float* out = (float*)d_out;
    (void)d_ws; (void)ws_size;

    const int B = in_sizes[1];  // 131072
    const int grid = B / 64;    // 2048 one-wave blocks = one full residency
    pushing_env_kernel<<<grid, 64, 0, stream>>>(u_seq, x1_0, v1_0, x2_0,
                                                v2_0, goal, out, B);
}